// Round 1
// 96.112 us; speedup vs baseline: 1.0160x; 1.0160x over previous
//
#include <hip/hip_runtime.h>
#include <stdint.h>
#include <stddef.h>

typedef __bf16 bf16_t;
typedef __bf16 bf16x8 __attribute__((ext_vector_type(8)));
typedef float  f32x4  __attribute__((ext_vector_type(4)));

#define NIMG 16
#define CIN  128
#define COUT 128
#define HH   56
#define WW   56
#define HW   (HH * WW)       // 3136
#define CDIM 58              // staged c extent: c = w+1, w = -1..56
#define LSTR 136             // LDS c-stride in bf16: 272B = 68 dwords -> bank stride 4
#define ROWPAIRS 28

// ---------- prologue: W[co][ci][3][3] fp32 -> Wt2 fragment-major bf16 ----------
// v2: one thread per 16B output run (rec,lane) -> 8 strided dword loads (L2-hit
// after first touch), ONE coalesced dwordx4 store. 36864 threads, 144 blocks.
// rec = (khkw*4+chunk)*8 + cotile; element (lane=l4*16+l15, j) =
//   W[co=cotile*16+l15][ci=chunk*32+l4*8+j][khkw]
__global__ void wtrans_kernel(const float* __restrict__ w, bf16_t* __restrict__ wt2) {
    int t = blockIdx.x * 256 + threadIdx.x;       // 36864 threads total
    int lane = t & 63, rec = t >> 6;
    int l15 = lane & 15, l4 = lane >> 4;
    int cotile = rec & 7, chunk = (rec >> 3) & 3, khkw = rec >> 5;
    int co  = cotile * 16 + l15;
    int ci0 = chunk * 32 + l4 * 8;
    const float* src = w + ((size_t)co * CIN + ci0) * 9 + khkw;
    bf16x8 o;
#pragma unroll
    for (int j = 0; j < 8; ++j) o[j] = (bf16_t)src[(size_t)j * 9];
    *(bf16x8*)(wt2 + (size_t)rec * 512 + (size_t)lane * 8) = o;
}

// ---------- fused conv: block = (n, 2 rows) x 128 co; 512 thr = 8 waves ----------
// wave = ks*4 + wc*2 + ws: tile 64sp x 64co (tc=4, ts=4), K split in half by ks
// (chunks {2ks,2ks+1} x 9 khkw = 18 phases). LDS cross-wave reduce at the end.
// i = khkw*2 + cs, cs = i&1; weight record offset for phase i (ks folded into base):
#define FRAG_OFF(I) ((size_t)((((I) >> 1) * 4 + ((I) & 1)) * 8) * 512)

#define MFMA_COL(Mv, TS, F0v, F1v, F2v, F3v)                                          \
    acc[0][TS] = __builtin_amdgcn_mfma_f32_16x16x32_bf16(F0v, Mv, acc[0][TS], 0,0,0); \
    acc[1][TS] = __builtin_amdgcn_mfma_f32_16x16x32_bf16(F1v, Mv, acc[1][TS], 0,0,0); \
    acc[2][TS] = __builtin_amdgcn_mfma_f32_16x16x32_bf16(F2v, Mv, acc[2][TS], 0,0,0); \
    acc[3][TS] = __builtin_amdgcn_mfma_f32_16x16x32_bf16(F3v, Mv, acc[3][TS], 0,0,0);

// All LDS B addresses = per-lane base + compile-time byte immediate (max 40,864 B,
// fits the 16-bit ds offset). Only ts=3 can clamp (ts<=2 max col = 49 <= 57), so
// ts=3 uses one of 3 precomputed clamped bases (selected at compile time per kw).
#define DO_PHASE(I, F0v, F1v, F2v, F3v) do {                                          \
    const int kh_ = ((I) >> 1) / 3, kw_ = ((I) >> 1) % 3, cs_ = (I) & 1;              \
    const bf16_t* b0_ = pB + (size_t)(kh_ * CDIM + kw_) * LSTR + cs_ * 32;            \
    const bf16_t* pb3_ = (kw_ == 0) ? pB3_0 : ((kw_ == 1) ? pB3_1 : pB3_2);           \
    const bf16_t* b3_ = pb3_ + (size_t)(kh_ * CDIM) * LSTR + cs_ * 32;                \
    bf16x8 m0_ = *(const bf16x8*)(b0_);                                               \
    bf16x8 m1_ = *(const bf16x8*)(b0_ + 16 * LSTR);                                   \
    bf16x8 m2_ = *(const bf16x8*)(b0_ + 32 * LSTR);                                   \
    bf16x8 m3_ = *(const bf16x8*)(b3_);                                               \
    __builtin_amdgcn_s_setprio(1);                                                    \
    MFMA_COL(m0_, 0, F0v, F1v, F2v, F3v)                                              \
    MFMA_COL(m1_, 1, F0v, F1v, F2v, F3v)                                              \
    MFMA_COL(m2_, 2, F0v, F1v, F2v, F3v)                                              \
    MFMA_COL(m3_, 3, F0v, F1v, F2v, F3v)                                              \
    __builtin_amdgcn_s_setprio(0);                                                    \
} while (0)

#define PREFETCH(I, F0v, F1v, F2v, F3v) do {                                          \
    const bf16_t* wp_ = wpbase + FRAG_OFF(I);                                         \
    F0v = *(const bf16x8*)(wp_);                                                      \
    F1v = *(const bf16x8*)(wp_ + 512);                                                \
    F2v = *(const bf16x8*)(wp_ + 1024);                                               \
    F3v = *(const bf16x8*)(wp_ + 1536);                                               \
} while (0)

__global__ __launch_bounds__(512, 4)
void conv_fused_kernel(const float* __restrict__ in, const bf16_t* __restrict__ Wt2,
                       const float* __restrict__ bias, float* __restrict__ out) {
    __shared__ __align__(16) unsigned char smem[65536];   // input stage 63104 B / reduce 65536 B
    bf16_t* inp = (bf16_t*)smem;

    // XCD-aware swizzle: grid 448 = 8 XCDs x 56 blocks. Default round-robin puts
    // adjacent row-pairs (which share 2 of 4 staged input rows) on DIFFERENT XCDs.
    // This bijective remap gives each XCD 56 consecutive logical blocks = 2 whole
    // images (3.2 MB input < 4 MiB L2) -> halo rows become L2 hits.
    const int bx0 = blockIdx.x;
    const int bx  = (bx0 & 7) * 56 + (bx0 >> 3);

    const int n  = bx / ROWPAIRS;
    const int h0 = (bx % ROWPAIRS) * 2;          // output rows h0,h0+1; input rows h0-1..h0+2

    const int tid  = threadIdx.x;
    const int lane = tid & 63;
    const int wave = tid >> 6;                   // 0..7
    const int ws  = wave & 1;                    // output row within pair
    const int wc  = (wave >> 1) & 1;             // co half (64)
    const int ks  = wave >> 2;                   // K half (chunks 2ks, 2ks+1)
    const int l15 = lane & 15;
    const int l4  = lane >> 4;

    // ---- stage input once: unit G = cig*232 + rr*58 + c (c fastest -> contiguous walk)
    // 3712 units = 7 full 512-thread sweeps + 128-thread tail
#pragma unroll
    for (int it = 0; it < 7; ++it) {
        int G = it * 512 + tid;
        {
            int cig = G / 232, rem = G - cig * 232;
            int rr  = rem / 58, c  = rem - rr * 58;
            int r_in = h0 - 1 + rr, w = c - 1;
            uint32_t u[8];
            if (r_in >= 0 && r_in < HH && w >= 0 && w < WW) {
                const float* src = in + (((size_t)n * CIN + cig * 8) * HH + r_in) * WW + w;
                float v[8];
#pragma unroll
                for (int j = 0; j < 8; ++j) v[j] = src[(size_t)j * HW];   // 8 independent loads
#pragma unroll
                for (int j = 0; j < 8; ++j) { bf16_t b = (bf16_t)v[j]; u[j] = *(const uint16_t*)&b; }
            } else {
#pragma unroll
                for (int j = 0; j < 8; ++j) u[j] = 0;
            }
            uint4 o;
            o.x = u[0] | (u[1] << 16); o.y = u[2] | (u[3] << 16);
            o.z = u[4] | (u[5] << 16); o.w = u[6] | (u[7] << 16);
            *(uint4*)&inp[(rr * CDIM + c) * LSTR + cig * 8] = o;
        }
    }
    if (tid < 128) {
        int G = 3584 + tid;
        int cig = G / 232, rem = G - cig * 232;
        int rr  = rem / 58, c  = rem - rr * 58;
        int r_in = h0 - 1 + rr, w = c - 1;
        uint32_t u[8];
        if (r_in >= 0 && r_in < HH && w >= 0 && w < WW) {
            const float* src = in + (((size_t)n * CIN + cig * 8) * HH + r_in) * WW + w;
            float v[8];
#pragma unroll
            for (int j = 0; j < 8; ++j) v[j] = src[(size_t)j * HW];
#pragma unroll
            for (int j = 0; j < 8; ++j) { bf16_t b = (bf16_t)v[j]; u[j] = *(const uint16_t*)&b; }
        } else {
#pragma unroll
            for (int j = 0; j < 8; ++j) u[j] = 0;
        }
        uint4 o;
        o.x = u[0] | (u[1] << 16); o.y = u[2] | (u[3] << 16);
        o.z = u[4] | (u[5] << 16); o.w = u[6] | (u[7] << 16);
        *(uint4*)&inp[(rr * CDIM + c) * LSTR + cig * 8] = o;
    }
    __syncthreads();

    f32x4 acc[4][4];                             // [co tile][sp tile]
#pragma unroll
    for (int a = 0; a < 4; ++a)
#pragma unroll
        for (int b2 = 0; b2 < 4; ++b2) acc[a][b2] = (f32x4){0.f, 0.f, 0.f, 0.f};

    // weight fragment base: rec = (khkw*4 + ks*2 + cs)*8 + wc*4 + tc
    const bf16_t* wpbase = Wt2 + (size_t)(ks * 16 + wc * 4) * 512 + (size_t)lane * 8;

    // LDS B bases (ws, ks, lane folded in; all phase offsets are compile-time imms)
    const bf16_t* pB = inp + (size_t)(ws * CDIM + l15) * LSTR + ks * 64 + l4 * 8;
    int c3_0 = 48 + l15;     if (c3_0 > 57) c3_0 = 57;    // ts=3 clamped cols per kw
    int c3_1 = 48 + l15 + 1; if (c3_1 > 57) c3_1 = 57;
    int c3_2 = 48 + l15 + 2; if (c3_2 > 57) c3_2 = 57;
    const bf16_t* pB3_0 = inp + (size_t)(ws * CDIM + c3_0) * LSTR + ks * 64 + l4 * 8;
    const bf16_t* pB3_1 = inp + (size_t)(ws * CDIM + c3_1) * LSTR + ks * 64 + l4 * 8;
    const bf16_t* pB3_2 = inp + (size_t)(ws * CDIM + c3_2) * LSTR + ks * 64 + l4 * 8;

    bf16x8 A0, A1, A2, A3, B0, B1, B2, B3;       // named regs, prefetch distance 2
    PREFETCH(0, A0, A1, A2, A3);
    PREFETCH(1, B0, B1, B2, B3);

#pragma unroll
    for (int ii = 0; ii < 8; ++ii) {
        const int i0 = ii * 2;
        DO_PHASE(i0, A0, A1, A2, A3);
        PREFETCH(i0 + 2, A0, A1, A2, A3);
        DO_PHASE(i0 + 1, B0, B1, B2, B3);
        PREFETCH(i0 + 3, B0, B1, B2, B3);
    }
    DO_PHASE(16, A0, A1, A2, A3);
    DO_PHASE(17, B0, B1, B2, B3);

    // ---- cross-wave K reduction through LDS (pair (ws,wc,ks=1) -> (ws,wc,ks=0))
    __syncthreads();                             // K-loop LDS reads done; safe to overwrite
    float* red = (float*)smem;
    const int q = wc * 2 + ws;                   // 0..3
    if (ks == 1) {
#pragma unroll
        for (int tc = 0; tc < 4; ++tc)
#pragma unroll
            for (int ts = 0; ts < 4; ++ts)
                *(f32x4*)(red + (size_t)q * 4096 + (tc * 4 + ts) * 256 + lane * 4) = acc[tc][ts];
    }
    __syncthreads();
    if (ks == 0) {
        const int h   = h0 + ws;
        const int co0 = wc * 64;
        float* obase = out + ((size_t)n * COUT) * HW + (size_t)h * WW;
#pragma unroll
        for (int tc = 0; tc < 4; ++tc) {
#pragma unroll
            for (int ts = 0; ts < 4; ++ts) {
                f32x4 oth = *(const f32x4*)(red + (size_t)q * 4096 + (tc * 4 + ts) * 256 + lane * 4);
                f32x4 r = acc[tc][ts] + oth;
                int w0 = ts * 16 + l15;
                if (w0 < WW) {
#pragma unroll
                    for (int i = 0; i < 4; ++i) {
                        int co = co0 + tc * 16 + l4 * 4 + i;
                        obase[(size_t)co * HW + w0] = r[i] + bias[co];
                    }
                }
            }
        }
    }
}

extern "C" void kernel_launch(void* const* d_in, const int* in_sizes, int n_in,
                              void* d_out, int out_size, void* d_ws, size_t ws_size,
                              hipStream_t stream) {
    const float* in   = (const float*)d_in[0];
    const float* wgt  = (const float*)d_in[1];
    const float* bias = (const float*)d_in[2];
    float* out = (float*)d_out;

    bf16_t* Wt2 = (bf16_t*)d_ws;                 // 294,912 B, fragment-major

    wtrans_kernel<<<144, 256, 0, stream>>>(wgt, Wt2);
    conv_fused_kernel<<<NIMG * ROWPAIRS, 512, 0, stream>>>(in, Wt2, bias, out);
}